// Round 5
// baseline (689.978 us; speedup 1.0000x reference)
//
#include <hip/hip_runtime.h>

typedef __attribute__((ext_vector_type(8))) short short8v;
typedef __attribute__((ext_vector_type(4))) float floatx4;

#define IND 5120

static __device__ __forceinline__ short f2bf(float f) {
    unsigned int u = __builtin_bit_cast(unsigned int, f);
    unsigned int r = (u + 0x7FFFu + ((u >> 16) & 1u)) >> 16;
    return (short)r;
}

// ---------------- pre: conv + residual + RMSNorm + router ----------------
// Writes n in tile-native swizzled bf16 layout: tiles of [128 rows][64 cols],
// short index within tile = (row&127)*64 + ((col&63) ^ ((row&7)<<3)).
__global__ __launch_bounds__(256)
void pre_kernel(const float* __restrict__ x, const float* __restrict__ conv_w,
                const float* __restrict__ conv_b, const float* __restrict__ rms_w,
                const float* __restrict__ router_w,
                short* __restrict__ nbf, float* __restrict__ combine)
{
    __shared__ float xs[6 * 1280];
    __shared__ float cw[3 * 1280];
    __shared__ float cb[1280];
    __shared__ float red[8];
    __shared__ float rred[16];

    const int t  = blockIdx.x;       // token 0..1023
    const int b  = t >> 8;
    const int tt = t & 255;
    const int s0 = tt * 4;
    const int tid = threadIdx.x;

    for (int idx = tid; idx < 7680; idx += 256) {
        int f = idx / 1280, d = idx - f * 1280;
        int s = s0 - 1 + f;
        float v = 0.f;
        if (s >= 0 && s < 1024) v = x[((size_t)b * 1024 + s) * 1280 + d];
        xs[idx] = v;
    }
    for (int idx = tid; idx < 3840; idx += 256) cw[idx] = conv_w[idx];
    for (int idx = tid; idx < 1280; idx += 256) cb[idx] = conv_b[idx];
    __syncthreads();

    float yv[20];
    float ss = 0.f;
#pragma unroll
    for (int j = 0; j < 20; ++j) {
        int k = tid + j * 256;           // IN index
        int f = k / 1280, d = k - f * 1280;
        float xm = xs[(f + 1) * 1280 + d];
        float y = xm + xs[f * 1280 + d] * cw[d * 3 + 0]
                     + xm               * cw[d * 3 + 1]
                     + xs[(f + 2) * 1280 + d] * cw[d * 3 + 2]
                     + cb[d];
        yv[j] = y;
        ss += y * y;
    }
    const int lane = tid & 63, wid = tid >> 6;
#pragma unroll
    for (int off = 32; off; off >>= 1) ss += __shfl_xor(ss, off);
    if (lane == 0) red[wid] = ss;
    __syncthreads();
    if (tid == 0) {
        float s4 = red[0] + red[1] + red[2] + red[3];
        red[4] = 1.0f / sqrtf(s4 * (1.0f / 5120.f) + 1e-8f);
    }
    __syncthreads();
    const float inv = red[4];

    const size_t rowbase = (size_t)(t >> 7) * 80 * 8192 + (size_t)(t & 127) * 64;
    const int xr = (t & 7) << 3;

    float r0 = 0.f, r1 = 0.f, r2 = 0.f, r3 = 0.f;
#pragma unroll
    for (int j = 0; j < 20; ++j) {
        int k = tid + j * 256;
        float nv = yv[j] * inv * rms_w[k];
        nbf[rowbase + (size_t)(k >> 6) * 8192 + ((k & 63) ^ xr)] = f2bf(nv);
        r0 += nv * router_w[k];
        r1 += nv * router_w[IND + k];
        r2 += nv * router_w[2 * IND + k];
        r3 += nv * router_w[3 * IND + k];
    }
#pragma unroll
    for (int off = 32; off; off >>= 1) {
        r0 += __shfl_xor(r0, off); r1 += __shfl_xor(r1, off);
        r2 += __shfl_xor(r2, off); r3 += __shfl_xor(r3, off);
    }
    if (lane == 0) { rred[wid*4+0]=r0; rred[wid*4+1]=r1; rred[wid*4+2]=r2; rred[wid*4+3]=r3; }
    __syncthreads();
    if (tid == 0) {
        float p[4];
#pragma unroll
        for (int e = 0; e < 4; ++e) {
            float lg = rred[e] + rred[4+e] + rred[8+e] + rred[12+e];
            p[e] = 1.0f / (1.0f + expf(-lg));
        }
        int i1 = 0;
        for (int e = 1; e < 4; ++e) if (p[e] > p[i1]) i1 = e;
        int i2 = (i1 == 0) ? 1 : 0;
        for (int e = 0; e < 4; ++e) if (e != i1 && p[e] > p[i2]) i2 = e;
        float wsum = p[i1] + p[i2] + 1e-6f;
        float c[4] = {0.f, 0.f, 0.f, 0.f};
        c[i1] = p[i1] / wsum;
        c[i2] = p[i2] / wsum;
        combine[t*4+0] = c[0]; combine[t*4+1] = c[1];
        combine[t*4+2] = c[2]; combine[t*4+3] = c[3];
    }
}

// B-operand staging: fp32 row-major source -> bf16 swizzled LDS tile.
// Per thread: 8 x float4 load, 16 x v_cvt_pk_bf16_f32, 8 x ds_write_b64.
static __device__ __forceinline__ void stage_b_fp32(
    const float* __restrict__ bsrc, int ldb, short* __restrict__ Bs, int tid)
{
#pragma unroll
    for (int i = 0; i < 8; ++i) {
        const int g   = i * 256 + tid;     // float4 index 0..2047
        const int row = g >> 4;            // 0..127
        const int cg  = g & 15;            // float4 within row
        float4 v = *(const float4*)(bsrc + (size_t)row * ldb + cg * 4);
        unsigned int u0, u1;
        asm("v_cvt_pk_bf16_f32 %0, %1, %2" : "=v"(u0) : "v"(v.x), "v"(v.y));
        asm("v_cvt_pk_bf16_f32 %0, %1, %2" : "=v"(u1) : "v"(v.z), "v"(v.w));
        const int off = row * 64 + ((cg * 4) ^ ((row & 7) << 3));
        uint2 w; w.x = u0; w.y = u1;
        *(uint2*)(Bs + off) = w;
    }
}

// ---------------- FC1 GEMM: h = relu(n @ W1_all^T + b1), routed cols scaled ----
// A = nbf tile-native. B = concat(sw1, ew1) fp32 row-major stride 5120,
// converted to bf16 during staging. Output tile-native bf16.
__global__ __launch_bounds__(256, 2)
void fc1_gemm(const short* __restrict__ A, const float* __restrict__ sw1,
              const float* __restrict__ ew1, const float* __restrict__ sb1,
              const float* __restrict__ eb1, const float* __restrict__ combine,
              short* __restrict__ Hout)
{
    __shared__ short As[8192];
    __shared__ short Bs[8192];
    const int tid  = threadIdx.x;
    const int lane = tid & 63;
    const int wid  = tid >> 6;
    const int wr   = wid >> 1, wc = wid & 1;
    const int n0   = blockIdx.x * 128;

    const float* bsrc = (n0 < 2048) ? (sw1 + (size_t)n0 * 5120)
                                    : (ew1 + (size_t)(n0 - 2048) * 5120);
    const short* at = A + (size_t)blockIdx.y * 80 * 8192;

    floatx4 acc[4][4] = {};

    for (int kt = 0; kt < 80; ++kt) {
#pragma unroll
        for (int i = 0; i < 4; ++i) {
            const int o = (i * 256 + tid) * 8;
            __builtin_amdgcn_global_load_lds(
                (const __attribute__((address_space(1))) void*)(at + o),
                (__attribute__((address_space(3))) void*)(As + o), 16, 0, 0);
        }
        stage_b_fp32(bsrc + kt * 64, 5120, Bs, tid);
        at += 8192;
        __syncthreads();
#pragma unroll
        for (int kk = 0; kk < 2; ++kk) {
            short8v af[4], bfr[4];
#pragma unroll
            for (int m = 0; m < 4; ++m) {
                const int r = wr * 64 + m * 16 + (lane & 15);
                const int c = (kk * 32 + (lane >> 4) * 8) ^ ((r & 7) << 3);
                af[m] = *(const short8v*)(As + r * 64 + c);
            }
#pragma unroll
            for (int n = 0; n < 4; ++n) {
                const int r = wc * 64 + n * 16 + (lane & 15);
                const int c = (kk * 32 + (lane >> 4) * 8) ^ ((r & 7) << 3);
                bfr[n] = *(const short8v*)(Bs + r * 64 + c);
            }
#pragma unroll
            for (int m = 0; m < 4; ++m)
#pragma unroll
                for (int n = 0; n < 4; ++n)
                    acc[m][n] = __builtin_amdgcn_mfma_f32_16x16x32_bf16(
                        af[m], bfr[n], acc[m][n], 0, 0, 0);
        }
        __syncthreads();
    }

    const int m0 = blockIdx.y * 128;
#pragma unroll
    for (int m = 0; m < 4; ++m) {
        const int rb = m0 + wr * 64 + m * 16 + ((lane >> 4) * 4);
#pragma unroll
        for (int n = 0; n < 4; ++n) {
            const int col = n0 + wc * 64 + n * 16 + (lane & 15);
#pragma unroll
            for (int r = 0; r < 4; ++r) {
                const int rowg = rb + r;
                float v = acc[m][n][r];
                v += (col < 2048) ? sb1[col] : eb1[col - 2048];
                v = fmaxf(v, 0.0f);
                if (col >= 2048) v *= combine[rowg * 4 + ((col - 2048) >> 11)];
                const size_t tb = ((size_t)(rowg >> 7) * 160 + (col >> 6)) * 8192;
                Hout[tb + (size_t)(rowg & 127) * 64 + ((col & 63) ^ ((rowg & 7) << 3))] = f2bf(v);
            }
        }
    }
}

// ---------------- FC2 GEMM: partial out = h_scaled @ W2_seg^T (split-K z=4) ----
__global__ __launch_bounds__(256, 2)
void fc2_gemm(const short* __restrict__ A, const float* __restrict__ sw2,
              const float* __restrict__ ew2, float* __restrict__ Pout)
{
    __shared__ short As[8192];
    __shared__ short Bs[8192];
    const int tid  = threadIdx.x;
    const int lane = tid & 63;
    const int wid  = tid >> 6;
    const int wr   = wid >> 1, wc = wid & 1;
    const int n0   = blockIdx.x * 128;

    const short* at = A + ((size_t)blockIdx.y * 160 + blockIdx.z * 40) * 8192;

    floatx4 acc[4][4] = {};

    for (int kt = 0; kt < 40; ++kt) {
#pragma unroll
        for (int i = 0; i < 4; ++i) {
            const int o = (i * 256 + tid) * 8;
            __builtin_amdgcn_global_load_lds(
                (const __attribute__((address_space(1))) void*)(at + o),
                (__attribute__((address_space(3))) void*)(As + o), 16, 0, 0);
        }
        const int kk = (blockIdx.z * 40 + kt) << 6;   // global k offset
        const float* bsrc = (kk < 2048)
            ? (sw2 + kk)
            : (ew2 + (size_t)((kk >> 11) - 1) * 4194304 + (kk & 2047));
        bsrc += (size_t)n0 * 2048;
        stage_b_fp32(bsrc, 2048, Bs, tid);
        at += 8192;
        __syncthreads();
#pragma unroll
        for (int kq = 0; kq < 2; ++kq) {
            short8v af[4], bfr[4];
#pragma unroll
            for (int m = 0; m < 4; ++m) {
                const int r = wr * 64 + m * 16 + (lane & 15);
                const int c = (kq * 32 + (lane >> 4) * 8) ^ ((r & 7) << 3);
                af[m] = *(const short8v*)(As + r * 64 + c);
            }
#pragma unroll
            for (int n = 0; n < 4; ++n) {
                const int r = wc * 64 + n * 16 + (lane & 15);
                const int c = (kq * 32 + (lane >> 4) * 8) ^ ((r & 7) << 3);
                bfr[n] = *(const short8v*)(Bs + r * 64 + c);
            }
#pragma unroll
            for (int m = 0; m < 4; ++m)
#pragma unroll
                for (int n = 0; n < 4; ++n)
                    acc[m][n] = __builtin_amdgcn_mfma_f32_16x16x32_bf16(
                        af[m], bfr[n], acc[m][n], 0, 0, 0);
        }
        __syncthreads();
    }

    const int m0 = blockIdx.y * 128;
    float* P = Pout + (size_t)blockIdx.z * (1024u * 2048u);
#pragma unroll
    for (int m = 0; m < 4; ++m) {
        const int rb = m0 + wr * 64 + m * 16 + ((lane >> 4) * 4);
#pragma unroll
        for (int n = 0; n < 4; ++n) {
            const int col = n0 + wc * 64 + n * 16 + (lane & 15);
#pragma unroll
            for (int r = 0; r < 4; ++r)
                P[(size_t)(rb + r) * 2048 + col] = acc[m][n][r];
        }
    }
}

// ---------------- split-K reduce + bias ----------------
__global__ __launch_bounds__(256)
void reduce_kernel(const float* __restrict__ part, const float* __restrict__ sb2,
                   const float* __restrict__ eb2, const float* __restrict__ combine,
                   float* __restrict__ out)
{
    const int idx  = blockIdx.x * 256 + threadIdx.x;  // float4 index
    const int base = idx * 4;
    const int row  = base >> 11;
    const int col  = base & 2047;
    const size_t NP = 1024u * 2048u;
    float4 s0 = *(const float4*)(part + base);
    float4 s1 = *(const float4*)(part + NP + base);
    float4 s2 = *(const float4*)(part + 2 * NP + base);
    float4 s3 = *(const float4*)(part + 3 * NP + base);
    const float c0 = combine[row * 4 + 0], c1 = combine[row * 4 + 1];
    const float c2 = combine[row * 4 + 2], c3 = combine[row * 4 + 3];
    float4 o;
    float* op = (float*)&o;
    const float* p0 = (const float*)&s0; const float* p1 = (const float*)&s1;
    const float* p2 = (const float*)&s2; const float* p3 = (const float*)&s3;
#pragma unroll
    for (int j = 0; j < 4; ++j) {
        const int c = col + j;
        float b2 = sb2[c] + c0 * eb2[c] + c1 * eb2[2048 + c]
                 + c2 * eb2[4096 + c] + c3 * eb2[6144 + c];
        op[j] = p0[j] + p1[j] + p2[j] + p3[j] + b2;
    }
    *(float4*)(out + base) = o;
}

extern "C" void kernel_launch(void* const* d_in, const int* in_sizes, int n_in,
                              void* d_out, int out_size, void* d_ws, size_t ws_size,
                              hipStream_t stream)
{
    const float* x        = (const float*)d_in[0];
    const float* conv_w   = (const float*)d_in[1];
    const float* conv_b   = (const float*)d_in[2];
    const float* rms_w    = (const float*)d_in[3];
    const float* router_w = (const float*)d_in[4];
    const float* sw1      = (const float*)d_in[5];
    const float* sb1      = (const float*)d_in[6];
    const float* sw2      = (const float*)d_in[7];
    const float* sb2      = (const float*)d_in[8];
    const float* ew1      = (const float*)d_in[9];
    const float* eb1      = (const float*)d_in[10];
    const float* ew2      = (const float*)d_in[11];
    const float* eb2      = (const float*)d_in[12];
    float* out = (float*)d_out;

    char* ws = (char*)d_ws;
    short* nbf     = (short*)(ws);                    // 1024*5120*2   = 10,485,760
    short* hbf     = (short*)(ws + 10485760);         // 1024*10240*2  = 20,971,520
    float* part2   = (float*)(ws + 31457280);         // 4*1024*2048*4 = 33,554,432
    float* combine = (float*)(ws + 65011712);         // 1024*4*4      = 16,384

    pre_kernel<<<1024, 256, 0, stream>>>(x, conv_w, conv_b, rms_w, router_w, nbf, combine);

    fc1_gemm<<<dim3(80, 8), 256, 0, stream>>>(
        nbf, sw1, ew1, sb1, eb1, combine, hbf);
    fc2_gemm<<<dim3(16, 8, 4), 256, 0, stream>>>(
        hbf, sw2, ew2, part2);

    reduce_kernel<<<2048, 256, 0, stream>>>(part2, sb2, eb2, combine, out);
}